// Round 1
// baseline (507.496 us; speedup 1.0000x reference)
//
#include <hip/hip_runtime.h>
#include <math.h>

namespace {
constexpr int B = 8, L = 200, H = 128, NH = 4;
constexpr float NEG = -4294967295.0f;              // -(2^32)+1
constexpr float QSCALE = 0.17677669529663687f;     // 1/sqrt(32)
}

// ---------------------------------------------------------------------------
// Kernel 1: Q/K/V projections (nn.Linear: y = x @ W.T + b), fused with
//   Q *= 1/sqrt(HD);  K += abs_pos_K;  V += abs_pos_V.
// grid = 3 * (B*L/8) blocks, 256 threads; each block does 8 rows of one proj.
// ---------------------------------------------------------------------------
extern "C" __global__ __launch_bounds__(256) void tama_proj(
    const float* __restrict__ queries, const float* __restrict__ keys,
    const float* __restrict__ apK, const float* __restrict__ apV,
    const float* __restrict__ Wq, const float* __restrict__ bq,
    const float* __restrict__ Wk, const float* __restrict__ bk,
    const float* __restrict__ Wv, const float* __restrict__ bv,
    float* __restrict__ Qs, float* __restrict__ KpK, float* __restrict__ VpV)
{
    const int nrb = (B * L) / 8;            // 200 row-blocks per projection
    const int which = blockIdx.x / nrb;     // 0:Q 1:K 2:V
    const int r0 = (blockIdx.x % nrb) * 8;
    const int t = threadIdx.x;

    const float* __restrict__ x    = (which == 0) ? queries : keys;
    const float* __restrict__ W    = (which == 0) ? Wq : (which == 1) ? Wk : Wv;
    const float* __restrict__ bias = (which == 0) ? bq : (which == 1) ? bk : bv;

    __shared__ float xs[8][H];
    *(float4*)(&xs[0][0] + t * 4) = *(const float4*)(x + (size_t)r0 * H + t * 4);
    __syncthreads();

    const int d  = t & (H - 1);
    const int rh = (t >> 7) * 4;            // local row base: 0 or 4
    float a0 = 0.f, a1 = 0.f, a2 = 0.f, a3 = 0.f;
    const float* __restrict__ wrow = W + (size_t)d * H;
    #pragma unroll 4
    for (int j = 0; j < H; ++j) {
        const float w = wrow[j];
        a0 += xs[rh + 0][j] * w;
        a1 += xs[rh + 1][j] * w;
        a2 += xs[rh + 2][j] * w;
        a3 += xs[rh + 3][j] * w;
    }
    const float bb = bias[d];
    float o[4] = {a0 + bb, a1 + bb, a2 + bb, a3 + bb};

    if (which == 0) {
        #pragma unroll
        for (int rr = 0; rr < 4; ++rr)
            Qs[(size_t)(r0 + rh + rr) * H + d] = o[rr] * QSCALE;
    } else if (which == 1) {
        #pragma unroll
        for (int rr = 0; rr < 4; ++rr) {
            const size_t idx = (size_t)(r0 + rh + rr) * H + d;
            KpK[idx] = o[rr] + apK[idx];
        }
    } else {
        #pragma unroll
        for (int rr = 0; rr < 4; ++rr) {
            const size_t idx = (size_t)(r0 + rh + rr) * H + d;
            VpV[idx] = o[rr] + apV[idx];
        }
    }
}

// ---------------------------------------------------------------------------
// Kernel 2: fused attention. One block per (b,q). 256 threads:
//   thread t -> column c4=(t&31)*4 (float4), k-row krow=t>>5, head h=(t&31)>>3.
// Phase A: scores for k<=q only (causal skip; skipped entirely for time-masked
//   rows). Phase B: prob-weighted V-sum; masked probs are exactly 0 so partial
//   tail chunks are numerically exact.
// ---------------------------------------------------------------------------
extern "C" __global__ __launch_bounds__(256) void tama_attn(
    const float* __restrict__ Qs, const float* __restrict__ KpK,
    const float* __restrict__ VpV, const int* __restrict__ time_mask,
    const float* __restrict__ tK, const float* __restrict__ tV,
    const float* __restrict__ dK, const float* __restrict__ dV,
    float* __restrict__ out)
{
    const int bq = (int)gridDim.x - 1 - (int)blockIdx.x;  // heavy (high-q) first
    const int b = bq / L, q = bq - b * L;
    const int t = threadIdx.x;

    __shared__ float p[NH][L];      // probs per head
    __shared__ float red[8][H];     // output reduction scratch

    const int c4   = (t & 31) * 4;
    const int krow = t >> 5;        // 0..7
    const int h    = (t & 31) >> 3; // head 0..3
    const int sg   = t & 7;

    const bool tmq = time_mask[b * L + q] != 0;  // row-mask: whole q row NEG
    const int kA = tmq ? 0 : (q + 1);            // score phase extent
    const int kB = tmq ? L : (q + 1);            // output phase extent

    const float4 q4 = *(const float4*)(Qs + (size_t)bq * H + c4);
    const float* __restrict__ tKb = tK + (size_t)bq * L * H;
    const float* __restrict__ dKb = dK + (size_t)bq * L * H;
    const float* __restrict__ kpb = KpK + (size_t)b * L * H;

    // ---- Phase A: scores ----
    for (int k0 = 0; k0 < kA; k0 += 8) {
        const int k = k0 + krow;    // always < L since kA <= L and k0 % 8 == 0
        const float4 a = *(const float4*)(tKb + (size_t)k * H + c4);
        const float4 c = *(const float4*)(dKb + (size_t)k * H + c4);
        const float4 e = *(const float4*)(kpb + (size_t)k * H + c4);
        float s = q4.x * (a.x + c.x + e.x) + q4.y * (a.y + c.y + e.y)
                + q4.z * (a.z + c.z + e.z) + q4.w * (a.w + c.w + e.w);
        s += __shfl_xor(s, 1);
        s += __shfl_xor(s, 2);
        s += __shfl_xor(s, 4);
        if (sg == 0) p[h][k] = s;   // k>q garbage masked in softmax
    }
    __syncthreads();

    // ---- Softmax: wave w handles head w; lanes cover k = lane + 64*i ----
    {
        const int wv = t >> 6;
        const int lane = t & 63;
        float s0 = p[wv][lane];
        float s1 = p[wv][lane + 64];
        float s2 = p[wv][lane + 128];
        float s3 = (lane < L - 192) ? p[wv][lane + 192] : NEG;
        if (tmq || lane > q)       s0 = NEG;
        if (tmq || lane + 64 > q)  s1 = NEG;
        if (tmq || lane + 128 > q) s2 = NEG;
        if (tmq || lane + 192 > q) s3 = NEG;   // always true for lane >= 8
        float m = fmaxf(fmaxf(s0, s1), fmaxf(s2, s3));
        #pragma unroll
        for (int off = 32; off; off >>= 1) m = fmaxf(m, __shfl_xor(m, off));
        const float e0 = __expf(s0 - m);       // exp(NEG-m) underflows to 0.0f
        const float e1 = __expf(s1 - m);
        const float e2 = __expf(s2 - m);
        const float e3 = (lane < L - 192) ? __expf(s3 - m) : 0.f;
        float sum = e0 + e1 + e2 + e3;
        #pragma unroll
        for (int off = 32; off; off >>= 1) sum += __shfl_xor(sum, off);
        const float inv = 1.0f / sum;
        p[wv][lane]       = e0 * inv;
        p[wv][lane + 64]  = e1 * inv;
        p[wv][lane + 128] = e2 * inv;
        if (lane < L - 192) p[wv][lane + 192] = e3 * inv;
    }
    __syncthreads();

    // ---- Phase B: out[c] = sum_k p[h][k] * (VpV + tV + dV)[k][c] ----
    const float* __restrict__ tVb = tV + (size_t)bq * L * H;
    const float* __restrict__ dVb = dV + (size_t)bq * L * H;
    const float* __restrict__ vpb = VpV + (size_t)b * L * H;
    float ax = 0.f, ay = 0.f, az = 0.f, aw = 0.f;
    for (int k0 = 0; k0 < kB; k0 += 8) {
        const int k = k0 + krow;
        const float pk = p[h][k];   // exactly 0 for masked k -> tail is exact
        const float4 a = *(const float4*)(tVb + (size_t)k * H + c4);
        const float4 c = *(const float4*)(dVb + (size_t)k * H + c4);
        const float4 e = *(const float4*)(vpb + (size_t)k * H + c4);
        ax += pk * (a.x + c.x + e.x);
        ay += pk * (a.y + c.y + e.y);
        az += pk * (a.z + c.z + e.z);
        aw += pk * (a.w + c.w + e.w);
    }
    red[krow][c4 + 0] = ax;
    red[krow][c4 + 1] = ay;
    red[krow][c4 + 2] = az;
    red[krow][c4 + 3] = aw;
    __syncthreads();
    if (t < 32) {
        float4 r = {0.f, 0.f, 0.f, 0.f};
        #pragma unroll
        for (int j = 0; j < 8; ++j) {
            r.x += red[j][t * 4 + 0];
            r.y += red[j][t * 4 + 1];
            r.z += red[j][t * 4 + 2];
            r.w += red[j][t * 4 + 3];
        }
        *(float4*)(out + (size_t)bq * H + t * 4) = r;
    }
}

// ---------------------------------------------------------------------------
extern "C" void kernel_launch(void* const* d_in, const int* in_sizes, int n_in,
                              void* d_out, int out_size, void* d_ws, size_t ws_size,
                              hipStream_t stream)
{
    const float* queries   = (const float*)d_in[0];
    const float* keys      = (const float*)d_in[1];
    const int*   time_mask = (const int*)d_in[2];
    // d_in[3] attn_mask unused: it is exactly triu(ones, k=1), i.e. (k > q)
    const float* tK  = (const float*)d_in[4];
    const float* tV  = (const float*)d_in[5];
    const float* dK  = (const float*)d_in[6];
    const float* dV  = (const float*)d_in[7];
    const float* apK = (const float*)d_in[8];
    const float* apV = (const float*)d_in[9];
    const float* Wq  = (const float*)d_in[10];
    const float* bqv = (const float*)d_in[11];
    const float* Wk  = (const float*)d_in[12];
    const float* bkv = (const float*)d_in[13];
    const float* Wv  = (const float*)d_in[14];
    const float* bvv = (const float*)d_in[15];

    float* Qs  = (float*)d_ws;                 // [B*L*H]
    float* KpK = Qs + (size_t)B * L * H;       // [B*L*H]
    float* VpV = KpK + (size_t)B * L * H;      // [B*L*H]  (total 2.46 MB)
    float* outp = (float*)d_out;

    hipLaunchKernelGGL(tama_proj, dim3(3 * (B * L) / 8), dim3(256), 0, stream,
                       queries, keys, apK, apV, Wq, bqv, Wk, bkv, Wv, bvv,
                       Qs, KpK, VpV);
    hipLaunchKernelGGL(tama_attn, dim3(B * L), dim3(256), 0, stream,
                       Qs, KpK, VpV, time_mask, tK, tV, dK, dV, outp);
}